// Round 3
// baseline (700.655 us; speedup 1.0000x reference)
//
#include <hip/hip_runtime.h>

// Problem constants: N=50000, E=800000, IN=128, HID=64, OUT=40
#define HID 64
#define JK_DIM 192
#define OUT_DIM 40

// ---------------------------------------------------------------------------
// GEMM with W held in registers: out[row, lane] = sum_k h[row,k] * W[k,lane].
// lane = output column (64 cols). Each wave grid-strides over rows.
// W column loads are coalesced (lane-consecutive); h row loads are wave-
// broadcast float4s. No LDS at all -> pure FMA inner loop.
// outStride lets us write either lin[N,64] or a column block of hcat[N,192].
// ---------------------------------------------------------------------------
template <int K, int MINW>
__global__ __launch_bounds__(256, MINW) void gemm_rw(const float* __restrict__ h,
                                                     const float* __restrict__ W,
                                                     float* __restrict__ out,
                                                     int outStride, int n) {
    int lane = threadIdx.x & 63;
    float w[K];
#pragma unroll
    for (int k = 0; k < K; ++k) w[k] = W[k * HID + lane];
    int wave = (blockIdx.x * 256 + threadIdx.x) >> 6;
    int nwaves = (gridDim.x * 256) >> 6;
    for (int row = wave; row < n; row += nwaves) {
        const float* hr = h + (long)row * K;
        float acc = 0.f;
#pragma unroll
        for (int k = 0; k < K; k += 4) {
            float4 hv = *(const float4*)(hr + k);
            acc += hv.x * w[k] + hv.y * w[k + 1] + hv.z * w[k + 2] + hv.w * w[k + 3];
        }
        out[(long)row * outStride + lane] = acc;
    }
}

// ---------------------------------------------------------------------------
// CSR build: histogram of dst, exclusive scan, atomic-slot fill.
// ---------------------------------------------------------------------------
__global__ __launch_bounds__(256) void hist_dst(const int* __restrict__ dst,
                                                int* __restrict__ deg, int E) {
    int e = blockIdx.x * 256 + threadIdx.x;
    if (e < E) atomicAdd(&deg[dst[e]], 1);
}

__global__ __launch_bounds__(256) void scan_a(const int* __restrict__ deg,
                                              int* __restrict__ off,
                                              int* __restrict__ bsum, int n) {
    __shared__ int tmp[256];
    int i = blockIdx.x * 256 + threadIdx.x;
    int v = (i < n) ? deg[i] : 0;
    tmp[threadIdx.x] = v;
    __syncthreads();
    for (int d = 1; d < 256; d <<= 1) {
        int t = (threadIdx.x >= d) ? tmp[threadIdx.x - d] : 0;
        __syncthreads();
        tmp[threadIdx.x] += t;
        __syncthreads();
    }
    if (i < n) off[i] = tmp[threadIdx.x] - v;
    if (threadIdx.x == 255) bsum[blockIdx.x] = tmp[255];
}

__global__ __launch_bounds__(256) void scan_b(int* __restrict__ bsum, int nblk) {
    __shared__ int tmp[256];
    int v = (threadIdx.x < nblk) ? bsum[threadIdx.x] : 0;
    tmp[threadIdx.x] = v;
    __syncthreads();
    for (int d = 1; d < 256; d <<= 1) {
        int t = (threadIdx.x >= d) ? tmp[threadIdx.x - d] : 0;
        __syncthreads();
        tmp[threadIdx.x] += t;
        __syncthreads();
    }
    if (threadIdx.x < nblk) bsum[threadIdx.x] = tmp[threadIdx.x] - v;
}

__global__ __launch_bounds__(256) void scan_c(int* __restrict__ off,
                                              const int* __restrict__ bsum,
                                              int* __restrict__ pos, int n) {
    int i = blockIdx.x * 256 + threadIdx.x;
    if (i >= n) return;
    int o = off[i] + bsum[blockIdx.x];
    off[i] = o;
    pos[i] = o;
}

__global__ __launch_bounds__(256) void fill_csr(const int* __restrict__ src,
                                                const int* __restrict__ dst,
                                                const float* __restrict__ ew,
                                                int* __restrict__ pos,
                                                int2* __restrict__ ecsr, int E) {
    int e = blockIdx.x * 256 + threadIdx.x;
    if (e >= E) return;
    int p = atomicAdd(&pos[dst[e]], 1);
    int2 v;
    v.x = src[e];
    v.y = __float_as_int(ew[e]);
    ecsr[p] = v;
}

// ---------------------------------------------------------------------------
// Aggregate + bias + ReLU. One wave per dst node (grid-stride), lane = column.
// Edge metadata for the node is preloaded in parallel (lane j takes edge j)
// and broadcast via __shfl, so the gather loads issue back-to-back with no
// serial pointer-chase. Writes into a column block of hcat[N,192].
// ---------------------------------------------------------------------------
__global__ __launch_bounds__(256) void aggregate(const float* __restrict__ lin,
                                                 const int2* __restrict__ ecsr,
                                                 const int* __restrict__ off,
                                                 const int* __restrict__ deg,
                                                 const float* __restrict__ bias,
                                                 float* __restrict__ hout, int n) {
    int lane = threadIdx.x & 63;
    float b = bias[lane];
    int wave = (blockIdx.x * 256 + threadIdx.x) >> 6;
    int nwaves = (gridDim.x * 256) >> 6;
    for (int node = wave; node < n; node += nwaves) {
        int start = off[node];
        int cnt = deg[node];
        float acc = 0.f;
        for (int base = 0; base < cnt; base += 64) {
            int m = min(64, cnt - base);
            int esrc = 0, ewbits = 0;
            if (lane < m) {
                int2 ev = ecsr[start + base + lane];
                esrc = ev.x;
                ewbits = ev.y;
            }
            int j = 0;
            for (; j + 4 <= m; j += 4) {
                int s0 = __shfl(esrc, j + 0, 64);
                int s1 = __shfl(esrc, j + 1, 64);
                int s2 = __shfl(esrc, j + 2, 64);
                int s3 = __shfl(esrc, j + 3, 64);
                float w0 = __int_as_float(__shfl(ewbits, j + 0, 64));
                float w1 = __int_as_float(__shfl(ewbits, j + 1, 64));
                float w2 = __int_as_float(__shfl(ewbits, j + 2, 64));
                float w3 = __int_as_float(__shfl(ewbits, j + 3, 64));
                float v0 = lin[(long)s0 * HID + lane];
                float v1 = lin[(long)s1 * HID + lane];
                float v2 = lin[(long)s2 * HID + lane];
                float v3 = lin[(long)s3 * HID + lane];
                acc += v0 * w0 + v1 * w1 + v2 * w2 + v3 * w3;
            }
            for (; j < m; ++j) {
                int s = __shfl(esrc, j, 64);
                float w = __int_as_float(__shfl(ewbits, j, 64));
                acc += lin[(long)s * HID + lane] * w;
            }
        }
        float v = acc + b;
        hout[(long)node * JK_DIM + lane] = v > 0.f ? v : 0.f;
    }
}

// ---------------------------------------------------------------------------
// Final: out[n,40] = hcat[n,192] @ Wlin[192,40] + blin.
// Wlin in LDS; each thread computes 8 rows x 1 col so LDS reads are
// amortized 8x (192 ds_read_b32 vs 1536 FMA per thread -> FMA bound).
// ---------------------------------------------------------------------------
__global__ __launch_bounds__(256) void final_gemm(const float* __restrict__ hcat,
                                                  const float* __restrict__ W,
                                                  const float* __restrict__ b,
                                                  float* __restrict__ out, int n) {
    __shared__ float Wl[JK_DIM * OUT_DIM];  // 30 KB
    for (int i = threadIdx.x; i < JK_DIM * OUT_DIM; i += 256) Wl[i] = W[i];
    __syncthreads();
    int col = threadIdx.x & 63;
    int grp = threadIdx.x >> 6;
    int row0 = blockIdx.x * 32 + grp * 8;
    if (col >= OUT_DIM || row0 >= n) return;
    float bc = b[col];
    float acc[8];
#pragma unroll
    for (int r = 0; r < 8; ++r) acc[r] = bc;

    if (row0 + 8 <= n) {
        const float* hr = hcat + (long)row0 * JK_DIM;
#pragma unroll 8
        for (int k = 0; k < JK_DIM; k += 4) {
            float w0 = Wl[(k + 0) * OUT_DIM + col];
            float w1 = Wl[(k + 1) * OUT_DIM + col];
            float w2 = Wl[(k + 2) * OUT_DIM + col];
            float w3 = Wl[(k + 3) * OUT_DIM + col];
#pragma unroll
            for (int r = 0; r < 8; ++r) {
                float4 hv = *(const float4*)(hr + (long)r * JK_DIM + k);
                acc[r] += hv.x * w0 + hv.y * w1 + hv.z * w2 + hv.w * w3;
            }
        }
#pragma unroll
        for (int r = 0; r < 8; ++r) out[(long)(row0 + r) * OUT_DIM + col] = acc[r];
    } else {
        int nr = n - row0;
        for (int k = 0; k < JK_DIM; ++k) {
            float w0 = Wl[k * OUT_DIM + col];
            for (int r = 0; r < nr; ++r)
                acc[r] += hcat[(long)(row0 + r) * JK_DIM + k] * w0;
        }
        for (int r = 0; r < nr; ++r) out[(long)(row0 + r) * OUT_DIM + col] = acc[r];
    }
}

// ---------------------------------------------------------------------------
extern "C" void kernel_launch(void* const* d_in, const int* in_sizes, int n_in,
                              void* d_out, int out_size, void* d_ws, size_t ws_size,
                              hipStream_t stream) {
    const float* x    = (const float*)d_in[0];
    const int*   ei   = (const int*)d_in[1];
    const float* ew   = (const float*)d_in[2];
    const float* W1   = (const float*)d_in[3];
    const float* b1   = (const float*)d_in[4];
    const float* W2   = (const float*)d_in[5];
    const float* b2   = (const float*)d_in[6];
    const float* W3   = (const float*)d_in[7];
    const float* b3   = (const float*)d_in[8];
    const float* Wlin = (const float*)d_in[9];
    const float* blin = (const float*)d_in[10];
    float* out = (float*)d_out;

    const int N = in_sizes[0] / 128;   // 50000
    const int E = in_sizes[2];         // 800000
    const int* src = ei;
    const int* dst = ei + E;

    // Workspace: lin [N,64] | hcat [N,192] | deg,off,pos [N] | bsum | ecsr [E]
    char* wsb = (char*)d_ws;
    float* lin  = (float*)wsb;                      wsb += (long)N * HID * 4;
    float* hcat = (float*)wsb;                      wsb += (long)N * JK_DIM * 4;
    int* deg    = (int*)wsb;                        wsb += (long)N * 4;
    int* off    = (int*)wsb;                        wsb += (long)N * 4;
    int* pos    = (int*)wsb;                        wsb += (long)N * 4;
    int* bsum   = (int*)wsb;                        wsb += 256 * 4;
    int2* ecsr  = (int2*)wsb;

    dim3 blk(256);
    const int nblkN = (N + 255) / 256;
    dim3 gN(nblkN);
    dim3 gE((E + 255) / 256);
    dim3 gAgg(2048);
    dim3 gFin((N + 31) / 32);

    float* h1 = hcat;           // columns [0,64)   of hcat[N,192]
    float* h2 = hcat + HID;     // columns [64,128)
    float* h3 = hcat + 2 * HID; // columns [128,192)

    // ---- CSR build (once per launch; inputs restored every call) ----
    hipMemsetAsync(deg, 0, (long)N * 4, stream);
    hist_dst<<<gE, blk, 0, stream>>>(dst, deg, E);
    scan_a<<<gN, blk, 0, stream>>>(deg, off, bsum, N);
    scan_b<<<1, blk, 0, stream>>>(bsum, nblkN);
    scan_c<<<gN, blk, 0, stream>>>(off, bsum, pos, N);
    fill_csr<<<gE, blk, 0, stream>>>(src, dst, ew, pos, ecsr, E);

    // ---- layer 1 (K=128) ----
    gemm_rw<128, 2><<<512, blk, 0, stream>>>(x, W1, lin, HID, N);
    aggregate<<<gAgg, blk, 0, stream>>>(lin, ecsr, off, deg, b1, h1, N);

    // ---- layer 2 (K=64), reads h1 (stride 192) via a strided-in gemm ----
    // gemm_rw expects contiguous rows; h1 rows have stride 192. Use lin as
    // the contiguous copy target: aggregate already wrote hcat, so gemm
    // reads hcat with stride via a dedicated path: simplest is to run the
    // K=64 gemm reading stride-192 rows.
    {
        // K=64 gemm reading stride-192 input rows: reuse gemm_rw by passing
        // a fake "row length" — instead we launch a strided variant below.
    }
    gemm_rw<64, 4><<<1024, blk, 0, stream>>>(nullptr, nullptr, nullptr, 0, 0); // no-op guard (n=0)
    // strided input handled by copying pointer math into aggregate's lin:
    // lin[row][c] must equal h1[row][c]; emulate with a small repack-free
    // trick: launch gemm reading h1 with stride JK_DIM.
    // (see gemm_rw_strided below)
    extern __global__ void gemm_rw_strided64(const float*, int, const float*, float*, int);
    gemm_rw_strided64<<<1024, blk, 0, stream>>>(h1, JK_DIM, W2, lin, N);
    aggregate<<<gAgg, blk, 0, stream>>>(lin, ecsr, off, deg, b2, h2, N);

    // ---- layer 3 ----
    gemm_rw_strided64<<<1024, blk, 0, stream>>>(h2, JK_DIM, W3, lin, N);
    aggregate<<<gAgg, blk, 0, stream>>>(lin, ecsr, off, deg, b3, h3, N);

    // ---- JK linear ----
    final_gemm<<<gFin, blk, 0, stream>>>(hcat, Wlin, blin, out, N);
}

// Strided-input K=64 GEMM: in rows have stride inStride (hcat column block).
__global__ __launch_bounds__(256, 4) void gemm_rw_strided64(const float* __restrict__ h,
                                                            int inStride,
                                                            const float* __restrict__ W,
                                                            float* __restrict__ out, int n) {
    int lane = threadIdx.x & 63;
    float w[64];
#pragma unroll
    for (int k = 0; k < 64; ++k) w[k] = W[k * HID + lane];
    int wave = (blockIdx.x * 256 + threadIdx.x) >> 6;
    int nwaves = (gridDim.x * 256) >> 6;
    for (int row = wave; row < n; row += nwaves) {
        const float* hr = h + (long)row * inStride;
        float acc = 0.f;
#pragma unroll
        for (int k = 0; k < 64; k += 4) {
            float4 hv = *(const float4*)(hr + k);
            acc += hv.x * w[k] + hv.y * w[k + 1] + hv.z * w[k + 2] + hv.w * w[k + 3];
        }
        out[(long)row * HID + lane] = acc;
    }
}

// Round 4
// 485.805 us; speedup vs baseline: 1.4423x; 1.4423x over previous
//
#include <hip/hip_runtime.h>

// Problem constants: N=50000, E=800000, IN=128, HID=64, OUT=40
#define HID 64
#define JK_DIM 192
#define OUT_DIM 40

// ---------------------------------------------------------------------------
// GEMM: out[row, lane] = sum_k h[row,k] * W[k,lane], W (K x 64) staged in LDS.
// lane = output column. Each wave computes 4 rows (16 rows/block) so the
// per-k LDS read of W is amortized over 4 FMAs x 4 k-values.
// inStride / outStride let us read/write column blocks of hcat[N,192].
// ---------------------------------------------------------------------------
template <int K>
__global__ __launch_bounds__(256) void gemm_lds(const float* __restrict__ h, int inStride,
                                                const float* __restrict__ W,
                                                float* __restrict__ out, int outStride,
                                                int n) {
    __shared__ float Wl[K * HID];
    for (int i = threadIdx.x; i < K * HID; i += 256) Wl[i] = W[i];
    __syncthreads();
    int lane = threadIdx.x & 63;
    int waveId = threadIdx.x >> 6;
    int row0 = (blockIdx.x * 4 + waveId) * 4;
    if (row0 >= n) return;
    const float* hr = h + (long)row0 * inStride;

    if (row0 + 4 <= n) {
        float acc0 = 0.f, acc1 = 0.f, acc2 = 0.f, acc3 = 0.f;
#pragma unroll
        for (int k = 0; k < K; k += 4) {
            float w0 = Wl[(k + 0) * HID + lane];
            float w1 = Wl[(k + 1) * HID + lane];
            float w2 = Wl[(k + 2) * HID + lane];
            float w3 = Wl[(k + 3) * HID + lane];
            float4 a = *(const float4*)(hr + 0L * inStride + k);
            float4 b = *(const float4*)(hr + 1L * inStride + k);
            float4 c = *(const float4*)(hr + 2L * inStride + k);
            float4 d = *(const float4*)(hr + 3L * inStride + k);
            acc0 += a.x * w0 + a.y * w1 + a.z * w2 + a.w * w3;
            acc1 += b.x * w0 + b.y * w1 + b.z * w2 + b.w * w3;
            acc2 += c.x * w0 + c.y * w1 + c.z * w2 + c.w * w3;
            acc3 += d.x * w0 + d.y * w1 + d.z * w2 + d.w * w3;
        }
        float* o = out + (long)row0 * outStride + lane;
        o[0L * outStride] = acc0;
        o[1L * outStride] = acc1;
        o[2L * outStride] = acc2;
        o[3L * outStride] = acc3;
    } else {
        for (int r = 0; r < n - row0; ++r) {
            float acc = 0.f;
            for (int k = 0; k < K; k += 4) {
                float4 a = *(const float4*)(hr + (long)r * inStride + k);
                acc += a.x * Wl[(k + 0) * HID + lane] + a.y * Wl[(k + 1) * HID + lane] +
                       a.z * Wl[(k + 2) * HID + lane] + a.w * Wl[(k + 3) * HID + lane];
            }
            out[(long)(row0 + r) * outStride + lane] = acc;
        }
    }
}

// ---------------------------------------------------------------------------
// CSR build: histogram of dst, exclusive scan, atomic-slot fill.
// ---------------------------------------------------------------------------
__global__ __launch_bounds__(256) void hist_dst(const int* __restrict__ dst,
                                                int* __restrict__ deg, int E) {
    int e = blockIdx.x * 256 + threadIdx.x;
    if (e < E) atomicAdd(&deg[dst[e]], 1);
}

__global__ __launch_bounds__(256) void scan_a(const int* __restrict__ deg,
                                              int* __restrict__ off,
                                              int* __restrict__ bsum, int n) {
    __shared__ int tmp[256];
    int i = blockIdx.x * 256 + threadIdx.x;
    int v = (i < n) ? deg[i] : 0;
    tmp[threadIdx.x] = v;
    __syncthreads();
    for (int d = 1; d < 256; d <<= 1) {
        int t = (threadIdx.x >= d) ? tmp[threadIdx.x - d] : 0;
        __syncthreads();
        tmp[threadIdx.x] += t;
        __syncthreads();
    }
    if (i < n) off[i] = tmp[threadIdx.x] - v;
    if (threadIdx.x == 255) bsum[blockIdx.x] = tmp[255];
}

__global__ __launch_bounds__(256) void scan_b(int* __restrict__ bsum, int nblk) {
    __shared__ int tmp[256];
    int v = (threadIdx.x < nblk) ? bsum[threadIdx.x] : 0;
    tmp[threadIdx.x] = v;
    __syncthreads();
    for (int d = 1; d < 256; d <<= 1) {
        int t = (threadIdx.x >= d) ? tmp[threadIdx.x - d] : 0;
        __syncthreads();
        tmp[threadIdx.x] += t;
        __syncthreads();
    }
    if (threadIdx.x < nblk) bsum[threadIdx.x] = tmp[threadIdx.x] - v;
}

__global__ __launch_bounds__(256) void scan_c(int* __restrict__ off,
                                              const int* __restrict__ bsum,
                                              int* __restrict__ pos, int n) {
    int i = blockIdx.x * 256 + threadIdx.x;
    if (i >= n) return;
    int o = off[i] + bsum[blockIdx.x];
    off[i] = o;
    pos[i] = o;
}

__global__ __launch_bounds__(256) void fill_csr(const int* __restrict__ src,
                                                const int* __restrict__ dst,
                                                const float* __restrict__ ew,
                                                int* __restrict__ pos,
                                                int2* __restrict__ ecsr, int E) {
    int e = blockIdx.x * 256 + threadIdx.x;
    if (e >= E) return;
    int p = atomicAdd(&pos[dst[e]], 1);
    int2 v;
    v.x = src[e];
    v.y = __float_as_int(ew[e]);
    ecsr[p] = v;
}

// ---------------------------------------------------------------------------
// Aggregate + bias + ReLU. One wave per dst node (grid-stride), lane = column.
// Edge metadata preloaded in parallel (lane j takes edge j), broadcast via
// __shfl; gather loads issue back-to-back. Writes a column block of hcat.
// ---------------------------------------------------------------------------
__global__ __launch_bounds__(256) void aggregate(const float* __restrict__ lin,
                                                 const int2* __restrict__ ecsr,
                                                 const int* __restrict__ off,
                                                 const int* __restrict__ deg,
                                                 const float* __restrict__ bias,
                                                 float* __restrict__ hout, int n) {
    int lane = threadIdx.x & 63;
    float b = bias[lane];
    int wave = (blockIdx.x * 256 + threadIdx.x) >> 6;
    int nwaves = (gridDim.x * 256) >> 6;
    for (int node = wave; node < n; node += nwaves) {
        int start = off[node];
        int cnt = deg[node];
        float acc = 0.f;
        for (int base = 0; base < cnt; base += 64) {
            int m = min(64, cnt - base);
            int esrc = 0, ewbits = 0;
            if (lane < m) {
                int2 ev = ecsr[start + base + lane];
                esrc = ev.x;
                ewbits = ev.y;
            }
            int j = 0;
            for (; j + 4 <= m; j += 4) {
                int s0 = __shfl(esrc, j + 0, 64);
                int s1 = __shfl(esrc, j + 1, 64);
                int s2 = __shfl(esrc, j + 2, 64);
                int s3 = __shfl(esrc, j + 3, 64);
                float w0 = __int_as_float(__shfl(ewbits, j + 0, 64));
                float w1 = __int_as_float(__shfl(ewbits, j + 1, 64));
                float w2 = __int_as_float(__shfl(ewbits, j + 2, 64));
                float w3 = __int_as_float(__shfl(ewbits, j + 3, 64));
                float v0 = lin[(long)s0 * HID + lane];
                float v1 = lin[(long)s1 * HID + lane];
                float v2 = lin[(long)s2 * HID + lane];
                float v3 = lin[(long)s3 * HID + lane];
                acc += v0 * w0 + v1 * w1 + v2 * w2 + v3 * w3;
            }
            for (; j < m; ++j) {
                int s = __shfl(esrc, j, 64);
                float w = __int_as_float(__shfl(ewbits, j, 64));
                acc += lin[(long)s * HID + lane] * w;
            }
        }
        float v = acc + b;
        hout[(long)node * JK_DIM + lane] = v > 0.f ? v : 0.f;
    }
}

// ---------------------------------------------------------------------------
// Final: out[n,40] = hcat[n,192] @ Wlin[192,40] + blin.
// Wlin in LDS; 8 rows per thread so each ds_read feeds 8 FMAs.
// ---------------------------------------------------------------------------
__global__ __launch_bounds__(256) void final_gemm(const float* __restrict__ hcat,
                                                  const float* __restrict__ W,
                                                  const float* __restrict__ b,
                                                  float* __restrict__ out, int n) {
    __shared__ float Wl[JK_DIM * OUT_DIM];  // 30 KB
    for (int i = threadIdx.x; i < JK_DIM * OUT_DIM; i += 256) Wl[i] = W[i];
    __syncthreads();
    int col = threadIdx.x & 63;
    int grp = threadIdx.x >> 6;
    int row0 = blockIdx.x * 32 + grp * 8;
    if (col >= OUT_DIM || row0 >= n) return;
    float bc = b[col];
    float acc[8];
#pragma unroll
    for (int r = 0; r < 8; ++r) acc[r] = bc;

    if (row0 + 8 <= n) {
        const float* hr = hcat + (long)row0 * JK_DIM;
#pragma unroll 4
        for (int k = 0; k < JK_DIM; k += 4) {
            float w0 = Wl[(k + 0) * OUT_DIM + col];
            float w1 = Wl[(k + 1) * OUT_DIM + col];
            float w2 = Wl[(k + 2) * OUT_DIM + col];
            float w3 = Wl[(k + 3) * OUT_DIM + col];
#pragma unroll
            for (int r = 0; r < 8; ++r) {
                float4 hv = *(const float4*)(hr + (long)r * JK_DIM + k);
                acc[r] += hv.x * w0 + hv.y * w1 + hv.z * w2 + hv.w * w3;
            }
        }
#pragma unroll
        for (int r = 0; r < 8; ++r) out[(long)(row0 + r) * OUT_DIM + col] = acc[r];
    } else {
        int nr = n - row0;
        for (int k = 0; k < JK_DIM; ++k) {
            float w0 = Wl[k * OUT_DIM + col];
            for (int r = 0; r < nr; ++r)
                acc[r] += hcat[(long)(row0 + r) * JK_DIM + k] * w0;
        }
        for (int r = 0; r < nr; ++r) out[(long)(row0 + r) * OUT_DIM + col] = acc[r];
    }
}

// ---------------------------------------------------------------------------
extern "C" void kernel_launch(void* const* d_in, const int* in_sizes, int n_in,
                              void* d_out, int out_size, void* d_ws, size_t ws_size,
                              hipStream_t stream) {
    const float* x    = (const float*)d_in[0];
    const int*   ei   = (const int*)d_in[1];
    const float* ew   = (const float*)d_in[2];
    const float* W1   = (const float*)d_in[3];
    const float* b1   = (const float*)d_in[4];
    const float* W2   = (const float*)d_in[5];
    const float* b2   = (const float*)d_in[6];
    const float* W3   = (const float*)d_in[7];
    const float* b3   = (const float*)d_in[8];
    const float* Wlin = (const float*)d_in[9];
    const float* blin = (const float*)d_in[10];
    float* out = (float*)d_out;

    const int N = in_sizes[0] / 128;   // 50000
    const int E = in_sizes[2];         // 800000
    const int* src = ei;
    const int* dst = ei + E;

    // Workspace: lin [N,64] | hcat [N,192] | deg,off,pos [N] | bsum | ecsr [E]
    char* wsb = (char*)d_ws;
    float* lin  = (float*)wsb;                      wsb += (long)N * HID * 4;
    float* hcat = (float*)wsb;                      wsb += (long)N * JK_DIM * 4;
    int* deg    = (int*)wsb;                        wsb += (long)N * 4;
    int* off    = (int*)wsb;                        wsb += (long)N * 4;
    int* pos    = (int*)wsb;                        wsb += (long)N * 4;
    int* bsum   = (int*)wsb;                        wsb += 256 * 4;
    int2* ecsr  = (int2*)wsb;

    dim3 blk(256);
    const int nblkN = (N + 255) / 256;
    dim3 gN(nblkN);
    dim3 gE((E + 255) / 256);
    dim3 gGemm((N + 15) / 16);             // 16 rows per block
    dim3 gAgg(2048);
    dim3 gFin((N + 31) / 32);

    float* h1 = hcat;           // columns [0,64)   of hcat[N,192]
    float* h2 = hcat + HID;     // columns [64,128)
    float* h3 = hcat + 2 * HID; // columns [128,192)

    // ---- CSR build (once per launch; ws is re-poisoned every call) ----
    hipMemsetAsync(deg, 0, (long)N * 4, stream);
    hist_dst<<<gE, blk, 0, stream>>>(dst, deg, E);
    scan_a<<<gN, blk, 0, stream>>>(deg, off, bsum, N);
    scan_b<<<1, blk, 0, stream>>>(bsum, nblkN);
    scan_c<<<gN, blk, 0, stream>>>(off, bsum, pos, N);
    fill_csr<<<gE, blk, 0, stream>>>(src, dst, ew, pos, ecsr, E);

    // ---- layer 1 (K=128) ----
    gemm_lds<128><<<gGemm, blk, 0, stream>>>(x, 128, W1, lin, HID, N);
    aggregate<<<gAgg, blk, 0, stream>>>(lin, ecsr, off, deg, b1, h1, N);

    // ---- layer 2 (K=64, reads h1 inside hcat with stride 192) ----
    gemm_lds<64><<<gGemm, blk, 0, stream>>>(h1, JK_DIM, W2, lin, HID, N);
    aggregate<<<gAgg, blk, 0, stream>>>(lin, ecsr, off, deg, b2, h2, N);

    // ---- layer 3 ----
    gemm_lds<64><<<gGemm, blk, 0, stream>>>(h2, JK_DIM, W3, lin, HID, N);
    aggregate<<<gAgg, blk, 0, stream>>>(lin, ecsr, off, deg, b3, h3, N);

    // ---- JK linear ----
    final_gemm<<<gFin, blk, 0, stream>>>(hcat, Wlin, blin, out, N);
}

// Round 5
// 465.086 us; speedup vs baseline: 1.5065x; 1.0445x over previous
//
#include <hip/hip_runtime.h>

// Problem constants: N=50000, E=800000, IN=128, HID=64, OUT=40
#define HID 64
#define JK_DIM 192
#define OUT_DIM 40
#define WT_PITCH 196   // LDS pitch for transposed Wlin: 16B-aligned, conflict-free

// ---------------------------------------------------------------------------
// GEMM: out[row, lane] = sum_k h[row,k] * W[k,lane], W (K x 64) in LDS.
// lane = output column (64 cols, all active). 8 rows per thread so each
// LDS read of W feeds 8 FMAs. inStride/outStride address hcat column blocks.
// ---------------------------------------------------------------------------
template <int K>
__global__ __launch_bounds__(256) void gemm_lds(const float* __restrict__ h, int inStride,
                                                const float* __restrict__ W,
                                                float* __restrict__ out, int outStride,
                                                int n) {
    __shared__ float Wl[K * HID];
    for (int i = threadIdx.x; i < K * HID; i += 256) Wl[i] = W[i];
    __syncthreads();
    int lane = threadIdx.x & 63;
    int waveId = threadIdx.x >> 6;
    int row0 = (blockIdx.x * 4 + waveId) * 8;
    if (row0 >= n) return;
    const float* hr = h + (long)row0 * inStride;

    if (row0 + 8 <= n) {
        float acc[8];
#pragma unroll
        for (int r = 0; r < 8; ++r) acc[r] = 0.f;
#pragma unroll 4
        for (int k = 0; k < K; k += 4) {
            float w0 = Wl[(k + 0) * HID + lane];
            float w1 = Wl[(k + 1) * HID + lane];
            float w2 = Wl[(k + 2) * HID + lane];
            float w3 = Wl[(k + 3) * HID + lane];
#pragma unroll
            for (int r = 0; r < 8; ++r) {
                float4 a = *(const float4*)(hr + (long)r * inStride + k);
                acc[r] += a.x * w0 + a.y * w1 + a.z * w2 + a.w * w3;
            }
        }
        float* o = out + (long)row0 * outStride + lane;
#pragma unroll
        for (int r = 0; r < 8; ++r) o[(long)r * outStride] = acc[r];
    } else {
        for (int r = 0; r < n - row0; ++r) {
            float acc = 0.f;
            for (int k = 0; k < K; k += 4) {
                float4 a = *(const float4*)(hr + (long)r * inStride + k);
                acc += a.x * Wl[(k + 0) * HID + lane] + a.y * Wl[(k + 1) * HID + lane] +
                       a.z * Wl[(k + 2) * HID + lane] + a.w * Wl[(k + 3) * HID + lane];
            }
            out[(long)(row0 + r) * outStride + lane] = acc;
        }
    }
}

// ---------------------------------------------------------------------------
// CSR build: histogram of dst, exclusive scan, atomic-slot fill.
// ---------------------------------------------------------------------------
__global__ __launch_bounds__(256) void hist_dst(const int* __restrict__ dst,
                                                int* __restrict__ deg, int E) {
    int e = blockIdx.x * 256 + threadIdx.x;
    if (e < E) atomicAdd(&deg[dst[e]], 1);
}

__global__ __launch_bounds__(256) void scan_a(const int* __restrict__ deg,
                                              int* __restrict__ off,
                                              int* __restrict__ bsum, int n) {
    __shared__ int tmp[256];
    int i = blockIdx.x * 256 + threadIdx.x;
    int v = (i < n) ? deg[i] : 0;
    tmp[threadIdx.x] = v;
    __syncthreads();
    for (int d = 1; d < 256; d <<= 1) {
        int t = (threadIdx.x >= d) ? tmp[threadIdx.x - d] : 0;
        __syncthreads();
        tmp[threadIdx.x] += t;
        __syncthreads();
    }
    if (i < n) off[i] = tmp[threadIdx.x] - v;
    if (threadIdx.x == 255) bsum[blockIdx.x] = tmp[255];
}

__global__ __launch_bounds__(256) void scan_b(int* __restrict__ bsum, int nblk) {
    __shared__ int tmp[256];
    int v = (threadIdx.x < nblk) ? bsum[threadIdx.x] : 0;
    tmp[threadIdx.x] = v;
    __syncthreads();
    for (int d = 1; d < 256; d <<= 1) {
        int t = (threadIdx.x >= d) ? tmp[threadIdx.x - d] : 0;
        __syncthreads();
        tmp[threadIdx.x] += t;
        __syncthreads();
    }
    if (threadIdx.x < nblk) bsum[threadIdx.x] = tmp[threadIdx.x] - v;
}

__global__ __launch_bounds__(256) void scan_c(int* __restrict__ off,
                                              const int* __restrict__ bsum,
                                              int* __restrict__ pos, int n) {
    int i = blockIdx.x * 256 + threadIdx.x;
    if (i >= n) return;
    int o = off[i] + bsum[blockIdx.x];
    off[i] = o;
    pos[i] = o;
}

__global__ __launch_bounds__(256) void fill_csr(const int* __restrict__ src,
                                                const int* __restrict__ dst,
                                                const float* __restrict__ ew,
                                                int* __restrict__ pos,
                                                int2* __restrict__ ecsr, int E) {
    int e = blockIdx.x * 256 + threadIdx.x;
    if (e >= E) return;
    int p = atomicAdd(&pos[dst[e]], 1);
    int2 v;
    v.x = src[e];
    v.y = __float_as_int(ew[e]);
    ecsr[p] = v;
}

// ---------------------------------------------------------------------------
// Aggregate + bias + ReLU. One wave per dst node (grid-stride).
// Wave = 4 groups x 16 lanes; group g handles edges g, g+4, g+8, ... with a
// float4 gather (16 lanes x 16B = full 256B row). Metadata for the wave's 4
// concurrent edges is a contiguous 32B read. Cross-group xor-shfl reduction
// once per node, then fused bias+ReLU and a single float4 row write.
// ---------------------------------------------------------------------------
__global__ __launch_bounds__(256) void aggregate(const float* __restrict__ lin,
                                                 const int2* __restrict__ ecsr,
                                                 const int* __restrict__ off,
                                                 const int* __restrict__ deg,
                                                 const float* __restrict__ bias,
                                                 float* __restrict__ hout, int n) {
    int lane = threadIdx.x & 63;
    int g = lane >> 4;          // edge group 0..3
    int cl = lane & 15;         // float4 column slot
    float4 b4 = *(const float4*)(bias + cl * 4);
    int wave = (blockIdx.x * 256 + threadIdx.x) >> 6;
    int nwaves = (gridDim.x * 256) >> 6;
    for (int node = wave; node < n; node += nwaves) {
        int start = off[node];
        int cnt = deg[node];
        float ax = 0.f, ay = 0.f, az = 0.f, aw = 0.f;
        for (int base = g; base < cnt; base += 4) {
            int2 ev = ecsr[start + base];
            float w = __int_as_float(ev.y);
            float4 v = *(const float4*)(lin + (long)ev.x * HID + cl * 4);
            ax += v.x * w;
            ay += v.y * w;
            az += v.z * w;
            aw += v.w * w;
        }
        // reduce the 4 groups (lanes l, l+16, l+32, l+48)
        ax += __shfl_xor(ax, 16, 64);
        ay += __shfl_xor(ay, 16, 64);
        az += __shfl_xor(az, 16, 64);
        aw += __shfl_xor(aw, 16, 64);
        ax += __shfl_xor(ax, 32, 64);
        ay += __shfl_xor(ay, 32, 64);
        az += __shfl_xor(az, 32, 64);
        aw += __shfl_xor(aw, 32, 64);
        if (lane < 16) {
            float4 o;
            o.x = fmaxf(ax + b4.x, 0.f);
            o.y = fmaxf(ay + b4.y, 0.f);
            o.z = fmaxf(az + b4.z, 0.f);
            o.w = fmaxf(aw + b4.w, 0.f);
            *(float4*)(hout + (long)node * JK_DIM + cl * 4) = o;
        }
    }
}

// ---------------------------------------------------------------------------
// Final: out[n,40] = hcat[n,192] @ Wlin[192,40] + blin.
// One wave (64 threads) per 64 rows. Thread = 8 rows x 5 cols register tile:
//   rg = lane>>3 selects the 8-row group, cg = lane&7 selects 5 cols.
// Wlin transposed into LDS (pitch 196): per 4-k chunk 5 ds_read_b128 +
// 8 coalesced float4 h loads feed 160 FMAs. All 64 lanes active.
// ---------------------------------------------------------------------------
__global__ __launch_bounds__(64) void final_gemm(const float* __restrict__ hcat,
                                                 const float* __restrict__ W,
                                                 const float* __restrict__ b,
                                                 float* __restrict__ out, int n) {
    __shared__ float Wt[OUT_DIM * WT_PITCH];  // 40*196*4 = 31360 B
    for (int i = threadIdx.x; i < JK_DIM * OUT_DIM; i += 64) {
        int k = i / OUT_DIM;
        int c = i - k * OUT_DIM;
        Wt[c * WT_PITCH + k] = W[i];
    }
    __syncthreads();
    int lane = threadIdx.x;
    int rg = lane >> 3;   // 0..7
    int cg = lane & 7;    // 0..7
    int c0 = cg * 5;
    int row0 = blockIdx.x * 64 + rg * 8;
    if (row0 >= n) return;

    float acc[8][5];
#pragma unroll
    for (int r = 0; r < 8; ++r)
#pragma unroll
        for (int i = 0; i < 5; ++i) acc[r][i] = 0.f;

    if (row0 + 8 <= n) {
        const float* hb = hcat + (long)row0 * JK_DIM;
#pragma unroll 2
        for (int k = 0; k < JK_DIM; k += 4) {
            float4 w0 = *(const float4*)(Wt + (c0 + 0) * WT_PITCH + k);
            float4 w1 = *(const float4*)(Wt + (c0 + 1) * WT_PITCH + k);
            float4 w2 = *(const float4*)(Wt + (c0 + 2) * WT_PITCH + k);
            float4 w3 = *(const float4*)(Wt + (c0 + 3) * WT_PITCH + k);
            float4 w4 = *(const float4*)(Wt + (c0 + 4) * WT_PITCH + k);
#pragma unroll
            for (int r = 0; r < 8; ++r) {
                float4 hv = *(const float4*)(hb + (long)r * JK_DIM + k);
                acc[r][0] += hv.x * w0.x + hv.y * w0.y + hv.z * w0.z + hv.w * w0.w;
                acc[r][1] += hv.x * w1.x + hv.y * w1.y + hv.z * w1.z + hv.w * w1.w;
                acc[r][2] += hv.x * w2.x + hv.y * w2.y + hv.z * w2.z + hv.w * w2.w;
                acc[r][3] += hv.x * w3.x + hv.y * w3.y + hv.z * w3.z + hv.w * w3.w;
                acc[r][4] += hv.x * w4.x + hv.y * w4.y + hv.z * w4.z + hv.w * w4.w;
            }
        }
#pragma unroll
        for (int r = 0; r < 8; ++r) {
            float* o = out + (long)(row0 + r) * OUT_DIM + c0;
#pragma unroll
            for (int i = 0; i < 5; ++i) o[i] = acc[r][i] + b[c0 + i];
        }
    } else {
        int nr = n - row0;  // 1..7
        for (int k = 0; k < JK_DIM; k += 4) {
            float4 w0 = *(const float4*)(Wt + (c0 + 0) * WT_PITCH + k);
            float4 w1 = *(const float4*)(Wt + (c0 + 1) * WT_PITCH + k);
            float4 w2 = *(const float4*)(Wt + (c0 + 2) * WT_PITCH + k);
            float4 w3 = *(const float4*)(Wt + (c0 + 3) * WT_PITCH + k);
            float4 w4 = *(const float4*)(Wt + (c0 + 4) * WT_PITCH + k);
            for (int r = 0; r < nr; ++r) {
                float4 hv = *(const float4*)(hcat + (long)(row0 + r) * JK_DIM + k);
                acc[r][0] += hv.x * w0.x + hv.y * w0.y + hv.z * w0.z + hv.w * w0.w;
                acc[r][1] += hv.x * w1.x + hv.y * w1.y + hv.z * w1.z + hv.w * w1.w;
                acc[r][2] += hv.x * w2.x + hv.y * w2.y + hv.z * w2.z + hv.w * w2.w;
                acc[r][3] += hv.x * w3.x + hv.y * w3.y + hv.z * w3.z + hv.w * w3.w;
                acc[r][4] += hv.x * w4.x + hv.y * w4.y + hv.z * w4.z + hv.w * w4.w;
            }
        }
        for (int r = 0; r < nr; ++r) {
            float* o = out + (long)(row0 + r) * OUT_DIM + c0;
            for (int i = 0; i < 5; ++i) o[i] = acc[r][i] + b[c0 + i];
        }
    }
}

// ---------------------------------------------------------------------------
extern "C" void kernel_launch(void* const* d_in, const int* in_sizes, int n_in,
                              void* d_out, int out_size, void* d_ws, size_t ws_size,
                              hipStream_t stream) {
    const float* x    = (const float*)d_in[0];
    const int*   ei   = (const int*)d_in[1];
    const float* ew   = (const float*)d_in[2];
    const float* W1   = (const float*)d_in[3];
    const float* b1   = (const float*)d_in[4];
    const float* W2   = (const float*)d_in[5];
    const float* b2   = (const float*)d_in[6];
    const float* W3   = (const float*)d_in[7];
    const float* b3   = (const float*)d_in[8];
    const float* Wlin = (const float*)d_in[9];
    const float* blin = (const float*)d_in[10];
    float* out = (float*)d_out;

    const int N = in_sizes[0] / 128;   // 50000
    const int E = in_sizes[2];         // 800000
    const int* src = ei;
    const int* dst = ei + E;

    // Workspace: lin [N,64] | hcat [N,192] | deg,off,pos [N] | bsum | ecsr [E]
    char* wsb = (char*)d_ws;
    float* lin  = (float*)wsb;                      wsb += (long)N * HID * 4;
    float* hcat = (float*)wsb;                      wsb += (long)N * JK_DIM * 4;
    int* deg    = (int*)wsb;                        wsb += (long)N * 4;
    int* off    = (int*)wsb;                        wsb += (long)N * 4;
    int* pos    = (int*)wsb;                        wsb += (long)N * 4;
    int* bsum   = (int*)wsb;                        wsb += 256 * 4;
    int2* ecsr  = (int2*)wsb;

    dim3 blk(256);
    const int nblkN = (N + 255) / 256;
    dim3 gN(nblkN);
    dim3 gE((E + 255) / 256);
    dim3 gGemm((N + 31) / 32);             // 32 rows per block (4 waves x 8)
    dim3 gAgg(2048);
    dim3 gFin((N + 63) / 64);              // 64 rows per 1-wave block

    float* h1 = hcat;           // columns [0,64)   of hcat[N,192]
    float* h2 = hcat + HID;     // columns [64,128)
    float* h3 = hcat + 2 * HID; // columns [128,192)

    // ---- CSR build (once per launch; ws is re-poisoned every call) ----
    hipMemsetAsync(deg, 0, (long)N * 4, stream);
    hist_dst<<<gE, blk, 0, stream>>>(dst, deg, E);
    scan_a<<<gN, blk, 0, stream>>>(deg, off, bsum, N);
    scan_b<<<1, blk, 0, stream>>>(bsum, nblkN);
    scan_c<<<gN, blk, 0, stream>>>(off, bsum, pos, N);
    fill_csr<<<gE, blk, 0, stream>>>(src, dst, ew, pos, ecsr, E);

    // ---- layer 1 (K=128) ----
    gemm_lds<128><<<gGemm, blk, 0, stream>>>(x, 128, W1, lin, HID, N);
    aggregate<<<gAgg, blk, 0, stream>>>(lin, ecsr, off, deg, b1, h1, N);

    // ---- layer 2 (K=64, reads h1 inside hcat with stride 192) ----
    gemm_lds<64><<<gGemm, blk, 0, stream>>>(h1, JK_DIM, W2, lin, HID, N);
    aggregate<<<gAgg, blk, 0, stream>>>(lin, ecsr, off, deg, b2, h2, N);

    // ---- layer 3 ----
    gemm_lds<64><<<gGemm, blk, 0, stream>>>(h2, JK_DIM, W3, lin, HID, N);
    aggregate<<<gAgg, blk, 0, stream>>>(lin, ecsr, off, deg, b3, h3, N);

    // ---- JK linear ----
    final_gemm<<<gFin, 64, 0, stream>>>(hcat, Wlin, blin, out, N);
}

// Round 6
// 375.560 us; speedup vs baseline: 1.8656x; 1.2384x over previous
//
#include <hip/hip_runtime.h>

// Problem constants: N=50000, E=800000, IN=128, HID=64, OUT=40
#define HID 64
#define JK_DIM 192
#define OUT_DIM 40
#define WT_PITCH 196   // LDS pitch for transposed Wlin in final_gemm
#define A_PITCH 68     // A-tile LDS pitch: 68*4B=272B (16B aligned), 2-way max bank alias

// ---------------------------------------------------------------------------
// Register-tiled GEMM: out[64x64 tile] = h[64 x K] @ W[K x 64].
// Block = 256 threads -> 16 row-groups x 16 col-groups, thread = 4x4 tile.
// A and W staged in LDS per BK=64 chunk with coalesced float4 loads; every
// lane reads distinct LDS data (no wave-broadcast VMEM). Per 4-k chunk per
// wave: 8 ds_read_b128 vs 64 v_fma -> FMA-issue bound.
// ---------------------------------------------------------------------------
template <int K>
__global__ __launch_bounds__(256) void gemm_tile(const float* __restrict__ h, int inStride,
                                                 const float* __restrict__ W,
                                                 float* __restrict__ out, int outStride,
                                                 int n) {
    __shared__ float As[64 * A_PITCH];   // 17408 B
    __shared__ float Ws[64 * HID];       // 16384 B
    int tid = threadIdx.x;
    int rg = tid >> 4;        // row group 0..15 (4 rows each)
    int cgrp = tid & 15;      // col group 0..15 (4 cols each)
    int c0 = cgrp * 4;
    int row0 = blockIdx.x * 64;
    if (row0 >= n) return;

    float acc[4][4] = {{0.f}};

    for (int kb = 0; kb < K; kb += 64) {
        // stage A: 64 rows x 64 k-floats, coalesced (16 float4 per row)
        for (int i = tid; i < 64 * 16; i += 256) {
            int r = i >> 4;
            int c4 = (i & 15) * 4;
            int grow = row0 + r;
            if (grow >= n) grow = n - 1;   // clamp (stores guarded below)
            float4 v = *(const float4*)(h + (long)grow * inStride + kb + c4);
            *(float4*)(As + r * A_PITCH + c4) = v;
        }
        // stage W: 64 k x 64 cols
        for (int i = tid; i < 64 * 16; i += 256) {
            int k = i >> 4;
            int c4 = (i & 15) * 4;
            *(float4*)(Ws + k * HID + c4) = *(const float4*)(W + (long)(kb + k) * HID + c4);
        }
        __syncthreads();
#pragma unroll 4
        for (int k = 0; k < 64; k += 4) {
            float4 w0 = *(const float4*)(Ws + (k + 0) * HID + c0);
            float4 w1 = *(const float4*)(Ws + (k + 1) * HID + c0);
            float4 w2 = *(const float4*)(Ws + (k + 2) * HID + c0);
            float4 w3 = *(const float4*)(Ws + (k + 3) * HID + c0);
#pragma unroll
            for (int r = 0; r < 4; ++r) {
                float4 a = *(const float4*)(As + (rg * 4 + r) * A_PITCH + k);
                acc[r][0] += a.x * w0.x + a.y * w1.x + a.z * w2.x + a.w * w3.x;
                acc[r][1] += a.x * w0.y + a.y * w1.y + a.z * w2.y + a.w * w3.y;
                acc[r][2] += a.x * w0.z + a.y * w1.z + a.z * w2.z + a.w * w3.z;
                acc[r][3] += a.x * w0.w + a.y * w1.w + a.z * w2.w + a.w * w3.w;
            }
        }
        __syncthreads();
    }
#pragma unroll
    for (int r = 0; r < 4; ++r) {
        int grow = row0 + rg * 4 + r;
        if (grow < n) {
            float4 o = make_float4(acc[r][0], acc[r][1], acc[r][2], acc[r][3]);
            *(float4*)(out + (long)grow * outStride + c0) = o;
        }
    }
}

// ---------------------------------------------------------------------------
// CSR build: histogram of dst, exclusive scan, atomic-slot fill.
// ---------------------------------------------------------------------------
__global__ __launch_bounds__(256) void hist_dst(const int* __restrict__ dst,
                                                int* __restrict__ deg, int E) {
    int e = blockIdx.x * 256 + threadIdx.x;
    if (e < E) atomicAdd(&deg[dst[e]], 1);
}

__global__ __launch_bounds__(256) void scan_a(const int* __restrict__ deg,
                                              int* __restrict__ off,
                                              int* __restrict__ bsum, int n) {
    __shared__ int tmp[256];
    int i = blockIdx.x * 256 + threadIdx.x;
    int v = (i < n) ? deg[i] : 0;
    tmp[threadIdx.x] = v;
    __syncthreads();
    for (int d = 1; d < 256; d <<= 1) {
        int t = (threadIdx.x >= d) ? tmp[threadIdx.x - d] : 0;
        __syncthreads();
        tmp[threadIdx.x] += t;
        __syncthreads();
    }
    if (i < n) off[i] = tmp[threadIdx.x] - v;
    if (threadIdx.x == 255) bsum[blockIdx.x] = tmp[255];
}

__global__ __launch_bounds__(256) void scan_b(int* __restrict__ bsum, int nblk) {
    __shared__ int tmp[256];
    int v = (threadIdx.x < nblk) ? bsum[threadIdx.x] : 0;
    tmp[threadIdx.x] = v;
    __syncthreads();
    for (int d = 1; d < 256; d <<= 1) {
        int t = (threadIdx.x >= d) ? tmp[threadIdx.x - d] : 0;
        __syncthreads();
        tmp[threadIdx.x] += t;
        __syncthreads();
    }
    if (threadIdx.x < nblk) bsum[threadIdx.x] = tmp[threadIdx.x] - v;
}

__global__ __launch_bounds__(256) void scan_c(int* __restrict__ off,
                                              const int* __restrict__ bsum,
                                              int* __restrict__ pos, int n) {
    int i = blockIdx.x * 256 + threadIdx.x;
    if (i >= n) return;
    int o = off[i] + bsum[blockIdx.x];
    off[i] = o;
    pos[i] = o;
}

__global__ __launch_bounds__(256) void fill_csr(const int* __restrict__ src,
                                                const int* __restrict__ dst,
                                                const float* __restrict__ ew,
                                                int* __restrict__ pos,
                                                int2* __restrict__ ecsr, int E) {
    int e = blockIdx.x * 256 + threadIdx.x;
    if (e >= E) return;
    int p = atomicAdd(&pos[dst[e]], 1);
    int2 v;
    v.x = src[e];
    v.y = __float_as_int(ew[e]);
    ecsr[p] = v;
}

// ---------------------------------------------------------------------------
// Aggregate + bias + ReLU. One wave per dst node (grid-stride).
// Wave = 4 groups x 16 lanes; group g handles edges g, g+4, ... with a
// float4 gather (16 lanes x 16B = full 256B row). Cross-group xor-shfl
// reduction once per node; fused bias+ReLU; single float4 row write.
// ---------------------------------------------------------------------------
__global__ __launch_bounds__(256) void aggregate(const float* __restrict__ lin,
                                                 const int2* __restrict__ ecsr,
                                                 const int* __restrict__ off,
                                                 const int* __restrict__ deg,
                                                 const float* __restrict__ bias,
                                                 float* __restrict__ hout, int n) {
    int lane = threadIdx.x & 63;
    int g = lane >> 4;          // edge group 0..3
    int cl = lane & 15;         // float4 column slot
    float4 b4 = *(const float4*)(bias + cl * 4);
    int wave = (blockIdx.x * 256 + threadIdx.x) >> 6;
    int nwaves = (gridDim.x * 256) >> 6;
    for (int node = wave; node < n; node += nwaves) {
        int start = off[node];
        int cnt = deg[node];
        float ax = 0.f, ay = 0.f, az = 0.f, aw = 0.f;
        for (int base = g; base < cnt; base += 4) {
            int2 ev = ecsr[start + base];
            float w = __int_as_float(ev.y);
            float4 v = *(const float4*)(lin + (long)ev.x * HID + cl * 4);
            ax += v.x * w;
            ay += v.y * w;
            az += v.z * w;
            aw += v.w * w;
        }
        ax += __shfl_xor(ax, 16, 64);
        ay += __shfl_xor(ay, 16, 64);
        az += __shfl_xor(az, 16, 64);
        aw += __shfl_xor(aw, 16, 64);
        ax += __shfl_xor(ax, 32, 64);
        ay += __shfl_xor(ay, 32, 64);
        az += __shfl_xor(az, 32, 64);
        aw += __shfl_xor(aw, 32, 64);
        if (lane < 16) {
            float4 o;
            o.x = fmaxf(ax + b4.x, 0.f);
            o.y = fmaxf(ay + b4.y, 0.f);
            o.z = fmaxf(az + b4.z, 0.f);
            o.w = fmaxf(aw + b4.w, 0.f);
            *(float4*)(hout + (long)node * JK_DIM + cl * 4) = o;
        }
    }
}

// ---------------------------------------------------------------------------
// Final: out[n,40] = hcat[n,192] @ Wlin[192,40] + blin.
// One wave per 64 rows; thread = 8 rows x 5 cols register tile; Wlin
// transposed into LDS (pitch 196, conflict-free b128 reads).
// ---------------------------------------------------------------------------
__global__ __launch_bounds__(64) void final_gemm(const float* __restrict__ hcat,
                                                 const float* __restrict__ W,
                                                 const float* __restrict__ b,
                                                 float* __restrict__ out, int n) {
    __shared__ float Wt[OUT_DIM * WT_PITCH];  // 31360 B
    for (int i = threadIdx.x; i < JK_DIM * OUT_DIM; i += 64) {
        int k = i / OUT_DIM;
        int c = i - k * OUT_DIM;
        Wt[c * WT_PITCH + k] = W[i];
    }
    __syncthreads();
    int lane = threadIdx.x;
    int rg = lane >> 3;   // 0..7
    int cg = lane & 7;    // 0..7
    int c0 = cg * 5;
    int row0 = blockIdx.x * 64 + rg * 8;
    if (row0 >= n) return;

    float acc[8][5];
#pragma unroll
    for (int r = 0; r < 8; ++r)
#pragma unroll
        for (int i = 0; i < 5; ++i) acc[r][i] = 0.f;

    if (row0 + 8 <= n) {
        const float* hb = hcat + (long)row0 * JK_DIM;
#pragma unroll 2
        for (int k = 0; k < JK_DIM; k += 4) {
            float4 w0 = *(const float4*)(Wt + (c0 + 0) * WT_PITCH + k);
            float4 w1 = *(const float4*)(Wt + (c0 + 1) * WT_PITCH + k);
            float4 w2 = *(const float4*)(Wt + (c0 + 2) * WT_PITCH + k);
            float4 w3 = *(const float4*)(Wt + (c0 + 3) * WT_PITCH + k);
            float4 w4 = *(const float4*)(Wt + (c0 + 4) * WT_PITCH + k);
#pragma unroll
            for (int r = 0; r < 8; ++r) {
                float4 hv = *(const float4*)(hb + (long)r * JK_DIM + k);
                acc[r][0] += hv.x * w0.x + hv.y * w0.y + hv.z * w0.z + hv.w * w0.w;
                acc[r][1] += hv.x * w1.x + hv.y * w1.y + hv.z * w1.z + hv.w * w1.w;
                acc[r][2] += hv.x * w2.x + hv.y * w2.y + hv.z * w2.z + hv.w * w2.w;
                acc[r][3] += hv.x * w3.x + hv.y * w3.y + hv.z * w3.z + hv.w * w3.w;
                acc[r][4] += hv.x * w4.x + hv.y * w4.y + hv.z * w4.z + hv.w * w4.w;
            }
        }
#pragma unroll
        for (int r = 0; r < 8; ++r) {
            float* o = out + (long)(row0 + r) * OUT_DIM + c0;
#pragma unroll
            for (int i = 0; i < 5; ++i) o[i] = acc[r][i] + b[c0 + i];
        }
    } else {
        int nr = n - row0;
        for (int k = 0; k < JK_DIM; k += 4) {
            float4 w0 = *(const float4*)(Wt + (c0 + 0) * WT_PITCH + k);
            float4 w1 = *(const float4*)(Wt + (c0 + 1) * WT_PITCH + k);
            float4 w2 = *(const float4*)(Wt + (c0 + 2) * WT_PITCH + k);
            float4 w3 = *(const float4*)(Wt + (c0 + 3) * WT_PITCH + k);
            float4 w4 = *(const float4*)(Wt + (c0 + 4) * WT_PITCH + k);
            for (int r = 0; r < nr; ++r) {
                float4 hv = *(const float4*)(hcat + (long)(row0 + r) * JK_DIM + k);
                acc[r][0] += hv.x * w0.x + hv.y * w0.y + hv.z * w0.z + hv.w * w0.w;
                acc[r][1] += hv.x * w1.x + hv.y * w1.y + hv.z * w1.z + hv.w * w1.w;
                acc[r][2] += hv.x * w2.x + hv.y * w2.y + hv.z * w2.z + hv.w * w2.w;
                acc[r][3] += hv.x * w3.x + hv.y * w3.y + hv.z * w3.z + hv.w * w3.w;
                acc[r][4] += hv.x * w4.x + hv.y * w4.y + hv.z * w4.z + hv.w * w4.w;
            }
        }
        for (int r = 0; r < nr; ++r) {
            float* o = out + (long)(row0 + r) * OUT_DIM + c0;
            for (int i = 0; i < 5; ++i) o[i] = acc[r][i] + b[c0 + i];
        }
    }
}

// ---------------------------------------------------------------------------
extern "C" void kernel_launch(void* const* d_in, const int* in_sizes, int n_in,
                              void* d_out, int out_size, void* d_ws, size_t ws_size,
                              hipStream_t stream) {
    const float* x    = (const float*)d_in[0];
    const int*   ei   = (const int*)d_in[1];
    const float* ew   = (const float*)d_in[2];
    const float* W1   = (const float*)d_in[3];
    const float* b1   = (const float*)d_in[4];
    const float* W2   = (const float*)d_in[5];
    const float* b2   = (const float*)d_in[6];
    const float* W3   = (const float*)d_in[7];
    const float* b3   = (const float*)d_in[8];
    const float* Wlin = (const float*)d_in[9];
    const float* blin = (const float*)d_in[10];
    float* out = (float*)d_out;

    const int N = in_sizes[0] / 128;   // 50000
    const int E = in_sizes[2];         // 800000
    const int* src = ei;
    const int* dst = ei + E;

    // Workspace: lin [N,64] | hcat [N,192] | deg,off,pos [N] | bsum | ecsr [E]
    char* wsb = (char*)d_ws;
    float* lin  = (float*)wsb;                      wsb += (long)N * HID * 4;
    float* hcat = (float*)wsb;                      wsb += (long)N * JK_DIM * 4;
    int* deg    = (int*)wsb;                        wsb += (long)N * 4;
    int* off    = (int*)wsb;                        wsb += (long)N * 4;
    int* pos    = (int*)wsb;                        wsb += (long)N * 4;
    int* bsum   = (int*)wsb;                        wsb += 256 * 4;
    int2* ecsr  = (int2*)wsb;

    dim3 blk(256);
    const int nblkN = (N + 255) / 256;
    dim3 gN(nblkN);
    dim3 gE((E + 255) / 256);
    dim3 gGemm((N + 63) / 64);             // 64-row tiles
    dim3 gAgg(2048);
    dim3 gFin((N + 63) / 64);

    float* h1 = hcat;           // columns [0,64)   of hcat[N,192]
    float* h2 = hcat + HID;     // columns [64,128)
    float* h3 = hcat + 2 * HID; // columns [128,192)

    // ---- CSR build (once per launch; ws is re-poisoned every call) ----
    hipMemsetAsync(deg, 0, (long)N * 4, stream);
    hist_dst<<<gE, blk, 0, stream>>>(dst, deg, E);
    scan_a<<<gN, blk, 0, stream>>>(deg, off, bsum, N);
    scan_b<<<1, blk, 0, stream>>>(bsum, nblkN);
    scan_c<<<gN, blk, 0, stream>>>(off, bsum, pos, N);
    fill_csr<<<gE, blk, 0, stream>>>(src, dst, ew, pos, ecsr, E);

    // ---- layer 1 (K=128) ----
    gemm_tile<128><<<gGemm, blk, 0, stream>>>(x, 128, W1, lin, HID, N);
    aggregate<<<gAgg, blk, 0, stream>>>(lin, ecsr, off, deg, b1, h1, N);

    // ---- layer 2 (K=64, reads h1 inside hcat with stride 192) ----
    gemm_tile<64><<<gGemm, blk, 0, stream>>>(h1, JK_DIM, W2, lin, HID, N);
    aggregate<<<gAgg, blk, 0, stream>>>(lin, ecsr, off, deg, b2, h2, N);

    // ---- layer 3 ----
    gemm_tile<64><<<gGemm, blk, 0, stream>>>(h2, JK_DIM, W3, lin, HID, N);
    aggregate<<<gAgg, blk, 0, stream>>>(lin, ecsr, off, deg, b3, h3, N);

    // ---- JK linear ----
    final_gemm<<<gFin, 64, 0, stream>>>(hcat, Wlin, blin, out, N);
}